// Round 6
// baseline (34.325 us; speedup 1.0000x reference)
//
#include <hip/hip_runtime.h>

#define IMGD 28
#define OUTD 26
#define NCLS 10
#define NIMG 64
#define UPB 29                       // padded float4 units per image per band (28 data + 1 pad)
#define BWORDS (NIMG * UPB * 4)      // 7424 floats = 29696 B per buffer
#define NBAND 7
#define THREADS 1024
#define LDSTRIDE 11

typedef float v2f __attribute__((ext_vector_type(2)));

__device__ __forceinline__ void gload_lds16(const float* gp, float* lp) {
    __builtin_amdgcn_global_load_lds(
        (const __attribute__((address_space(1))) void*)gp,
        (__attribute__((address_space(3))) void*)lp, 16, 0, 0);
}

// Stage one disjoint 4-row band (input rows r0..r0+3) of 64 images into buf.
// LDS layout: [img][unit], unit stride UPB=29 (odd) -> ds_read_b128 group
// (29*img + u) % 8 covers all 8 bank-quads across lanes: conflict-free.
// Source addresses are linear within each image's 448B row-block -> coalesced.
__device__ __forceinline__ void stage_band(const float* __restrict__ x,
                                           int img_base, int B, int r0,
                                           float* buf, int wv, int lane)
{
#pragma unroll
    for (int it = 0; it < 2; ++it) {
        const int fw = it * 16 + wv;             // wave-uniform chunk id
        if (fw < UPB) {
            const int f = fw * 64 + lane;        // flat unit 0..1855
            const int g = f / UPB;               // image 0..63
            const int s = f - g * UPB;           // LDS unit slot 0..28
            const int q = (s == 28) ? 27 : s;    // pad slot -> dup (same 64B line)
            int gi = img_base + g; if (gi >= B) gi = B - 1;
            const float* gp = x + (size_t)gi * (IMGD * IMGD) + r0 * IMGD + q * 4;
            gload_lds16(gp, buf + fw * 256);     // uniform base + lane*16B
        }
    }
}

// read NU float4 units (band row br, unit col u0) of image `lane`
template<int NU>
__device__ __forceinline__ void read_row(const float* buf, int lane, int br, int u0,
                                         float* dst)
{
    const float4* b4 = (const float4*)buf;
#pragma unroll
    for (int u = 0; u < NU; ++u) {
        float4 a = b4[lane * UPB + br * 7 + u0 + u];
        dst[4*u+0] = a.x; dst[4*u+1] = a.y; dst[4*u+2] = a.z; dst[4*u+3] = a.w;
    }
}

// one output row: conv3x3 (tree) + relu + rank-1 GEMM update, W wave-uniform
template<int WID, int OFF>
__device__ __forceinline__ void conv_row(const float* X, const float* Y, const float* Z,
                                         const float (&kk)[9],
                                         const float* __restrict__ wr, v2f* acc)
{
#pragma unroll
    for (int c = 0; c < WID; ++c) {
        float p0 = fmaf(X[OFF+c], kk[0], X[OFF+c+1] * kk[1]);
        p0 = fmaf(X[OFF+c+2], kk[2], p0);
        float p1 = fmaf(Y[OFF+c], kk[3], Y[OFF+c+1] * kk[4]);
        p1 = fmaf(Y[OFF+c+2], kk[5], p1);
        float p2 = fmaf(Z[OFF+c], kk[6], Z[OFF+c+1] * kk[7]);
        p2 = fmaf(Z[OFF+c+2], kk[8], p2);
        float v = fmaxf((p0 + p1) + p2, 0.0f);
        const float* w = wr + c * NCLS;          // wave-uniform -> s_load
#pragma unroll
        for (int p = 0; p < 5; ++p) {
            v2f wv2 = *(const v2f*)(w + 2 * p);
            v2f vv; vv[0] = v; vv[1] = v;
            acc[p] += vv * wv2;                  // v_pk_fma_f32
        }
    }
}

// Full band pipeline, SINGLE barrier per phase:
//   [vmcnt(0) = own band-k loads landed] [barrier: all landed & all band-(k-1)
//   reads done] [stage band k+1 -> other buffer] [compute band k]
// rg=0: 2 within-band output rows. rg=1: 2 straddle rows via register halo.
template<int WID, int NU, int OFF>
__device__ __forceinline__ void run_all(
    const float* __restrict__ x, int img_base, int B,
    float* lds0, int wv, int lane, int rg, int u0, int c0,
    const float* __restrict__ cw, const float* __restrict__ Wp, v2f* acc)
{
    float kk[9];
#pragma unroll
    for (int i = 0; i < 9; ++i) kk[i] = cw[i];   // uniform -> SGPRs

    float S[2][4 * NU];                          // halo rows (rg=1 only)

    stage_band(x, img_base, B, 0, lds0, wv, lane);   // prologue: band 0 only

    for (int k = 0; k < NBAND; ++k) {
        // only outstanding loads are this wave's band-k chunk
        asm volatile("s_waitcnt vmcnt(0)" ::: "memory");
        __builtin_amdgcn_s_barrier();            // band k fully landed, band k-1 reads done

        // issue next band's loads BEFORE compute: queue stays full across phase
        if (k + 1 < NBAND)
            stage_band(x, img_base, B, 4 * (k + 1),
                       lds0 + ((k + 1) & 1) * BWORDS, wv, lane);

        const float* buf = lds0 + (k & 1) * BWORDS;

        if (rg == 0) {
            // outputs r=4k, 4k+1 from band rows 0..3
            float R[4][4 * NU];
#pragma unroll
            for (int br = 0; br < 4; ++br) read_row<NU>(buf, lane, br, u0, R[br]);
            conv_row<WID, OFF>(R[0], R[1], R[2], kk,
                               Wp + ((size_t)(4 * k) * OUTD + c0) * NCLS, acc);
            conv_row<WID, OFF>(R[1], R[2], R[3], kk,
                               Wp + ((size_t)(4 * k + 1) * OUTD + c0) * NCLS, acc);
        } else {
            if (k > 0) {
                // straddle outputs r=4k-2, 4k-1: saved rows + band k rows 0,1
                float T[2][4 * NU];
                read_row<NU>(buf, lane, 0, u0, T[0]);
                read_row<NU>(buf, lane, 1, u0, T[1]);
                conv_row<WID, OFF>(S[0], S[1], T[0], kk,
                                   Wp + ((size_t)(4 * k - 2) * OUTD + c0) * NCLS, acc);
                conv_row<WID, OFF>(S[1], T[0], T[1], kk,
                                   Wp + ((size_t)(4 * k - 1) * OUTD + c0) * NCLS, acc);
            }
            if (k < NBAND - 1) {                 // save halo before buffer recycled
                read_row<NU>(buf, lane, 2, u0, S[0]);
                read_row<NU>(buf, lane, 3, u0, S[1]);
            }
        }
    }
}

__global__ __launch_bounds__(THREADS, 8) void fused_conv_relu_fc(
    const float* __restrict__ x,      // [B, 784]
    const float* __restrict__ cw,     // [9]
    const float* __restrict__ Wp,     // [676, 10]
    const float* __restrict__ bp,     // [10]
    float* __restrict__ out,          // [B, 10]
    int B)
{
    __shared__ float lds[2 * BWORDS];            // 59392 B -> 2 blocks/CU

    const int lane = threadIdx.x & 63;
    const int wv   = __builtin_amdgcn_readfirstlane((int)(threadIdx.x >> 6));
    const int rg   = wv >> 3;                    // 0: within-band, 1: straddle
    const int cs   = wv & 7;                     // col strip
    const int img_base = blockIdx.x * NIMG;

    v2f acc[5];
#pragma unroll
    for (int p = 0; p < 5; ++p) { acc[p][0] = 0.0f; acc[p][1] = 0.0f; }

    // strips: 5 x width-4 + 3 x width-2 (identical barrier sequences)
    if      (cs < 5)  run_all<4,2,0>(x, img_base, B, lds, wv, lane, rg, cs, 4*cs, cw, Wp, acc);
    else if (cs == 5) run_all<2,1,0>(x, img_base, B, lds, wv, lane, rg, 5,  20,   cw, Wp, acc);
    else if (cs == 6) run_all<2,2,2>(x, img_base, B, lds, wv, lane, rg, 5,  22,   cw, Wp, acc);
    else              run_all<2,1,0>(x, img_base, B, lds, wv, lane, rg, 6,  24,   cw, Wp, acc);

    __syncthreads();                             // all band-6 reads done before overlay

    // partials -> LDS overlay (stride 11: 2 lanes/bank -> free)
    float* part = lds;                           // 16*64*11*4 = 45056 B < 59392
    float* myp = &part[(wv * 64 + lane) * LDSTRIDE];
#pragma unroll
    for (int p = 0; p < 5; ++p) { myp[2*p] = acc[p][0]; myp[2*p+1] = acc[p][1]; }
    __syncthreads();

    // combine 16 partials + bias; coalesced 640-float store per block
    const int o = threadIdx.x;
    if (o < NIMG * NCLS) {
        const int im = o / NCLS;
        const int c  = o - im * NCLS;
        float s = bp[c];
#pragma unroll
        for (int w2 = 0; w2 < 16; ++w2)
            s += part[(w2 * 64 + im) * LDSTRIDE + c];
        if (img_base + im < B)
            out[(size_t)(img_base + im) * NCLS + c] = s;
    }
}

extern "C" void kernel_launch(void* const* d_in, const int* in_sizes, int n_in,
                              void* d_out, int out_size, void* d_ws, size_t ws_size,
                              hipStream_t stream) {
    const float* x  = (const float*)d_in[0];
    const float* cw = (const float*)d_in[1];
    const float* Wp = (const float*)d_in[2];
    const float* bp = (const float*)d_in[3];
    float* out = (float*)d_out;

    const int B = in_sizes[0] / (IMGD * IMGD);   // 32768
    const int grid = (B + NIMG - 1) / NIMG;      // 512 blocks x 16 waves

    fused_conv_relu_fc<<<grid, THREADS, 0, stream>>>(x, cw, Wp, bp, out, B);
}

// Round 7
// 32.247 us; speedup vs baseline: 1.0644x; 1.0644x over previous
//
#include <hip/hip_runtime.h>

#define IMGD 28
#define OUTD 26
#define NCLS 10
#define NIMG 64
#define UPB 35                       // float4 units per image per 5-row band (5*28/4), odd -> bank-clean
#define UPB_T 21                     // tail band: 3 rows (3*28/4), odd -> bank-clean
#define BWORDS (NIMG * UPB * 4)      // 8960 floats = 35840 B per buffer
#define NBAND 6
#define THREADS 1024
#define LDSTRIDE 11

typedef float v2f __attribute__((ext_vector_type(2)));

__device__ __forceinline__ void gload_lds16(const float* gp, float* lp) {
    __builtin_amdgcn_global_load_lds(
        (const __attribute__((address_space(1))) void*)gp,
        (__attribute__((address_space(3))) void*)lp, 16, 0, 0);
}

// Stage one disjoint band (UNITS float4-units per image, rows r0..) of 64
// images. LDS: [img][unit] linear, stride UNITS (odd) -> ds_read_b128 at
// (UNITS*lane + u) % 8 covers all 8 bank-quads: conflict-free.
// Global source: lane-consecutive units within each image's contiguous
// band block -> coalesced (~16 lines per wave-instr).
template<int UNITS>
__device__ __forceinline__ void stage_band(const float* __restrict__ x,
                                           int img_base, int B, int r0,
                                           float* buf, int wv, int lane)
{
#pragma unroll
    for (int it = 0; it < 3; ++it) {
        const int fw = it * 16 + wv;             // wave-uniform chunk id
        if (fw < UNITS) {
            const int f = fw * 64 + lane;        // flat unit index
            const int g = f / UNITS;             // image 0..63 (constexpr div)
            const int s = f - g * UNITS;         // unit within band
            int gi = img_base + g; if (gi >= B) gi = B - 1;
            const float* gp = x + (size_t)gi * (IMGD * IMGD) + r0 * IMGD + s * 4;
            gload_lds16(gp, buf + fw * 256);     // uniform base + lane*16B
        }
    }
}

// read NU float4 units (band row br, unit col u0) of image `lane`, layout stride STRIDE
template<int NU, int STRIDE>
__device__ __forceinline__ void read_row(const float* buf, int lane, int br, int u0,
                                         float* dst)
{
    const float4* b4 = (const float4*)buf;
#pragma unroll
    for (int u = 0; u < NU; ++u) {
        float4 a = b4[lane * STRIDE + br * 7 + u0 + u];
        dst[4*u+0] = a.x; dst[4*u+1] = a.y; dst[4*u+2] = a.z; dst[4*u+3] = a.w;
    }
}

// one output row: conv3x3 (tree) + relu + rank-1 GEMM update, W wave-uniform
template<int WID, int OFF>
__device__ __forceinline__ void conv_row(const float* X, const float* Y, const float* Z,
                                         const float (&kk)[9],
                                         const float* __restrict__ wr, v2f* acc)
{
#pragma unroll
    for (int c = 0; c < WID; ++c) {
        float p0 = fmaf(X[OFF+c], kk[0], X[OFF+c+1] * kk[1]);
        p0 = fmaf(X[OFF+c+2], kk[2], p0);
        float p1 = fmaf(Y[OFF+c], kk[3], Y[OFF+c+1] * kk[4]);
        p1 = fmaf(Y[OFF+c+2], kk[5], p1);
        float p2 = fmaf(Z[OFF+c], kk[6], Z[OFF+c+1] * kk[7]);
        p2 = fmaf(Z[OFF+c+2], kk[8], p2);
        float v = fmaxf((p0 + p1) + p2, 0.0f);
        const float* w = wr + c * NCLS;          // wave-uniform -> s_load
#pragma unroll
        for (int p = 0; p < 5; ++p) {
            v2f wv2 = *(const v2f*)(w + 2 * p);
            v2f vv; vv[0] = v; vv[1] = v;
            acc[p] += vv * wv2;                  // v_pk_fma_f32
        }
    }
}

// Round-5 proven schedule (depth-2, counted vmcnt, double barrier), 5-row bands:
// bands 0..4 = rows 5k..5k+4 (35 units), band 5 = rows 25..27 (21 units).
// rg0: within rows 5k,5k+1,5k+2 (rolling 3-row window of the 5 staged rows).
// rg1: straddle rows 5k-2,5k-1 from 2-row register halo (band k-1 rows 3,4).
template<int WID, int NU, int OFF>
__device__ __forceinline__ void run_all(
    const float* __restrict__ x, int img_base, int B,
    float* lds0, int wv, int lane, int rg, int u0, int c0,
    const float* __restrict__ cw, const float* __restrict__ Wp, v2f* acc)
{
    float kk[9];
#pragma unroll
    for (int i = 0; i < 9; ++i) kk[i] = cw[i];   // uniform -> SGPRs

    float S0[4 * NU], S1[4 * NU];                // halo rows (rg=1 only)

    stage_band<UPB>(x, img_base, B, 0, lds0,          wv, lane);
    stage_band<UPB>(x, img_base, B, 5, lds0 + BWORDS, wv, lane);

    for (int k = 0; k < NBAND - 1; ++k) {        // k = 0..4
        // wait band k; leave band k+1 in flight (counted by this wave's share)
        if (k == NBAND - 2) {                    // band 5 (21 units) in flight
            if (wv < 5) asm volatile("s_waitcnt vmcnt(2)" ::: "memory");
            else        asm volatile("s_waitcnt vmcnt(1)" ::: "memory");
        } else {                                 // 35-unit band in flight
            if (wv < 3) asm volatile("s_waitcnt vmcnt(3)" ::: "memory");
            else        asm volatile("s_waitcnt vmcnt(2)" ::: "memory");
        }
        __builtin_amdgcn_s_barrier();            // band k landed for all waves

        const float* buf = lds0 + (k & 1) * BWORDS;

        if (rg == 0) {
            // outputs 5k,5k+1,5k+2 from band rows 0..4 (rolling window)
            float Ra[4*NU], Rb[4*NU], Rc[4*NU], Rd[4*NU], Re[4*NU];
            read_row<NU, UPB>(buf, lane, 0, u0, Ra);
            read_row<NU, UPB>(buf, lane, 1, u0, Rb);
            read_row<NU, UPB>(buf, lane, 2, u0, Rc);
            conv_row<WID, OFF>(Ra, Rb, Rc, kk,
                               Wp + ((size_t)(5 * k) * OUTD + c0) * NCLS, acc);
            read_row<NU, UPB>(buf, lane, 3, u0, Rd);
            conv_row<WID, OFF>(Rb, Rc, Rd, kk,
                               Wp + ((size_t)(5 * k + 1) * OUTD + c0) * NCLS, acc);
            read_row<NU, UPB>(buf, lane, 4, u0, Re);
            conv_row<WID, OFF>(Rc, Rd, Re, kk,
                               Wp + ((size_t)(5 * k + 2) * OUTD + c0) * NCLS, acc);
        } else {
            if (k > 0) {
                // straddle outputs 5k-2,5k-1: halo rows + band k rows 0,1
                float Ta[4*NU], Tb[4*NU];
                read_row<NU, UPB>(buf, lane, 0, u0, Ta);
                read_row<NU, UPB>(buf, lane, 1, u0, Tb);
                conv_row<WID, OFF>(S0, S1, Ta, kk,
                                   Wp + ((size_t)(5 * k - 2) * OUTD + c0) * NCLS, acc);
                conv_row<WID, OFF>(S1, Ta, Tb, kk,
                                   Wp + ((size_t)(5 * k - 1) * OUTD + c0) * NCLS, acc);
            }
            read_row<NU, UPB>(buf, lane, 3, u0, S0);   // halo = band k rows 3,4
            read_row<NU, UPB>(buf, lane, 4, u0, S1);
        }

        if (k <= NBAND - 3) {                    // stage band k+2 into buf[k&1]
            asm volatile("" ::: "memory");
            __builtin_amdgcn_s_barrier();        // all reads of buf[k&1] done
            asm volatile("" ::: "memory");
            if (k == 3)
                stage_band<UPB_T>(x, img_base, B, 25, lds0 + (k & 1) * BWORDS, wv, lane);
            else
                stage_band<UPB>(x, img_base, B, 5 * (k + 2), lds0 + (k & 1) * BWORDS, wv, lane);
        }
    }

    // tail: band 5 (rows 25..27, stride 21) in buf1
    asm volatile("s_waitcnt vmcnt(0)" ::: "memory");
    __builtin_amdgcn_s_barrier();
    const float* buf = lds0 + BWORDS;
    if (rg == 0) {
        float Ta[4*NU], Tb[4*NU], Tc[4*NU];
        read_row<NU, UPB_T>(buf, lane, 0, u0, Ta);
        read_row<NU, UPB_T>(buf, lane, 1, u0, Tb);
        read_row<NU, UPB_T>(buf, lane, 2, u0, Tc);
        conv_row<WID, OFF>(Ta, Tb, Tc, kk,
                           Wp + ((size_t)25 * OUTD + c0) * NCLS, acc);
    } else {
        float Ta[4*NU], Tb[4*NU];
        read_row<NU, UPB_T>(buf, lane, 0, u0, Ta);
        read_row<NU, UPB_T>(buf, lane, 1, u0, Tb);
        conv_row<WID, OFF>(S0, S1, Ta, kk,
                           Wp + ((size_t)23 * OUTD + c0) * NCLS, acc);
        conv_row<WID, OFF>(S1, Ta, Tb, kk,
                           Wp + ((size_t)24 * OUTD + c0) * NCLS, acc);
    }
}

__global__ __launch_bounds__(THREADS, 8) void fused_conv_relu_fc(
    const float* __restrict__ x,      // [B, 784]
    const float* __restrict__ cw,     // [9]
    const float* __restrict__ Wp,     // [676, 10]
    const float* __restrict__ bp,     // [10]
    float* __restrict__ out,          // [B, 10]
    int B)
{
    __shared__ float lds[2 * BWORDS];            // 71680 B -> 2 blocks/CU

    const int lane = threadIdx.x & 63;
    const int wv   = __builtin_amdgcn_readfirstlane((int)(threadIdx.x >> 6));
    const int rg   = wv >> 3;                    // 0: within-band, 1: straddle
    const int cs   = wv & 7;                     // col strip
    const int img_base = blockIdx.x * NIMG;

    v2f acc[5];
#pragma unroll
    for (int p = 0; p < 5; ++p) { acc[p][0] = 0.0f; acc[p][1] = 0.0f; }

    // strips: 5 x width-4 + 3 x width-2 (identical barrier sequences)
    if      (cs < 5)  run_all<4,2,0>(x, img_base, B, lds, wv, lane, rg, cs, 4*cs, cw, Wp, acc);
    else if (cs == 5) run_all<2,1,0>(x, img_base, B, lds, wv, lane, rg, 5,  20,   cw, Wp, acc);
    else if (cs == 6) run_all<2,2,2>(x, img_base, B, lds, wv, lane, rg, 5,  22,   cw, Wp, acc);
    else              run_all<2,1,0>(x, img_base, B, lds, wv, lane, rg, 6,  24,   cw, Wp, acc);

    __syncthreads();                             // all band-5 reads done before overlay

    // partials -> LDS overlay (stride 11: 2 lanes/bank -> free)
    float* part = lds;                           // 16*64*11*4 = 45056 B < 71680
    float* myp = &part[(wv * 64 + lane) * LDSTRIDE];
#pragma unroll
    for (int p = 0; p < 5; ++p) { myp[2*p] = acc[p][0]; myp[2*p+1] = acc[p][1]; }
    __syncthreads();

    // combine 16 partials + bias; coalesced 640-float store per block
    const int o = threadIdx.x;
    if (o < NIMG * NCLS) {
        const int im = o / NCLS;
        const int c  = o - im * NCLS;
        float s = bp[c];
#pragma unroll
        for (int w2 = 0; w2 < 16; ++w2)
            s += part[(w2 * 64 + im) * LDSTRIDE + c];
        if (img_base + im < B)
            out[(size_t)(img_base + im) * NCLS + c] = s;
    }
}

extern "C" void kernel_launch(void* const* d_in, const int* in_sizes, int n_in,
                              void* d_out, int out_size, void* d_ws, size_t ws_size,
                              hipStream_t stream) {
    const float* x  = (const float*)d_in[0];
    const float* cw = (const float*)d_in[1];
    const float* Wp = (const float*)d_in[2];
    const float* bp = (const float*)d_in[3];
    float* out = (float*)d_out;

    const int B = in_sizes[0] / (IMGD * IMGD);   // 32768
    const int grid = (B + NIMG - 1) / NIMG;      // 512 blocks x 16 waves

    fused_conv_relu_fc<<<grid, THREADS, 0, stream>>>(x, cw, Wp, bp, out, B);
}